// Round 15
// baseline (138.744 us; speedup 1.0000x reference)
//
#include <hip/hip_runtime.h>
#include <stdint.h>

// Problem constants
constexpr int C_IN  = 512;
constexpr int HW    = 784;            // 28*28
constexpr int NB    = 32;
constexpr int M_TOT = NB * HW;        // 25088 = 98*256
constexpr int N_TOT = 2000;
constexpr int NPAD  = 2048;
constexpr int IMG_STRIDE = C_IN * HW;
constexpr int OUT_BATCH  = N_TOT * HW;

// GEMM: 256x128 block, 4 waves (wave 128x64), BK=32, ZERO-LDS fragment
// streaming over fragment-major layout + XCD-locality remap (round-14's
// proven fix for the round-12 FETCH=164MB L2-miss failure).
constexpr int TBM = 256;
constexpr int TBN = 128;
constexpr int NKT = C_IN / 32;        // 16

constexpr int PREPA_BLOCKS = M_TOT / 64;   // 392 (64 rows = 4 mtiles each)
constexpr int PREPW_BLOCKS = NPAD / 16;    // 128 (16 rows = 1 ntile each)

typedef __attribute__((ext_vector_type(8))) short bf16x8;
typedef __attribute__((ext_vector_type(4))) float f32x4;

__device__ __forceinline__ uint16_t f2bf(float f) {
    union { float f; uint32_t u; } x; x.f = f;
    return (uint16_t)((x.u + 0x8000u) >> 16);
}

// non-temporal 16B LOAD only (nt stores measured +100 MB WRITE, round 13)
__device__ __forceinline__ f32x4 nt_load4(const float* p) {
    return __builtin_nontemporal_load((const f32x4*)p);
}

// ---------------------------------------------------------------------------
// prep: blocks [0,392): A -> fragment-major bf16 (Afr), fused s2
//       blocks [392,520): W -> fragment-major bf16 (Wfr, rows>=N_TOT zero), w2
// Fragment layout: fi = mtile*16 + kt;  Afr[fi*64 + lane] (16 B) =
//   A[mtile*16 + (lane&15)][kt*32 + (lane>>4)*8 ..+7]
// -> a wave's MFMA fragment load is one contiguous aligned 1 KB stream.
__global__ __launch_bounds__(256) void prep_kernel(const float* __restrict__ in,
                                                   const float* __restrict__ w,
                                                   short* __restrict__ Afr,
                                                   short* __restrict__ Wfr,
                                                   float* __restrict__ s2,
                                                   float* __restrict__ w2) {
    __shared__ __align__(16) char T[64 * 512 * 2];
    __shared__ float red[16][64];

    const int t = threadIdx.x;
    const int wvl = t >> 6, l = t & 63;

    if (blockIdx.x >= PREPA_BLOCKS) {
        // ---------------- prep_w: one ntile (16 rows) per block ----------------
        const int b = blockIdx.x - PREPA_BLOCKS;   // 0..127
        const int r = t >> 4;                      // row in tile 0..15
        const int c = t & 15;                      // k-chunk of 32
        const int p = b * 16 + r;
        float s = 0.f;
        if (p < N_TOT) {
            const float* base = w + (size_t)p * C_IN + c * 32;
#pragma unroll
            for (int j = 0; j < 4; ++j) {
                f32x4 x = nt_load4(base + j * 8);
                f32x4 y = nt_load4(base + j * 8 + 4);
                s += x[0]*x[0] + x[1]*x[1] + x[2]*x[2] + x[3]*x[3]
                   + y[0]*y[0] + y[1]*y[1] + y[2]*y[2] + y[3]*y[3];
                bf16x8 o;
                o[0] = (short)f2bf(x[0]); o[1] = (short)f2bf(x[1]);
                o[2] = (short)f2bf(x[2]); o[3] = (short)f2bf(x[3]);
                o[4] = (short)f2bf(y[0]); o[5] = (short)f2bf(y[1]);
                o[6] = (short)f2bf(y[2]); o[7] = (short)f2bf(y[3]);
                const int ch = c * 4 + j;
                uint32_t bb = (uint32_t)r * 1024u + (uint32_t)ch * 16u;
                bb ^= ((bb >> 12) & 7u) << 4;
                *(bf16x8*)(T + bb) = o;
            }
        } else {
            bf16x8 z = (bf16x8)0;
#pragma unroll
            for (int j = 0; j < 4; ++j) {
                const int ch = c * 4 + j;
                uint32_t bb = (uint32_t)r * 1024u + (uint32_t)ch * 16u;
                bb ^= ((bb >> 12) & 7u) << 4;
                *(bf16x8*)(T + bb) = z;
            }
        }
        red[r][c] = s;
        __syncthreads();
        if (t < 16) {
            float ss = 0.f;
#pragma unroll
            for (int c2 = 0; c2 < 16; ++c2) ss += red[t][c2];
            w2[b * 16 + t] = ss;
        }
        short* dstW = Wfr + (size_t)b * 16 * 512;
#pragma unroll
        for (int i = 0; i < 4; ++i) {
            const int kt = i * 4 + wvl;
            const int row = l & 15;
            const int ch  = kt * 4 + (l >> 4);
            uint32_t bb = (uint32_t)row * 1024u + (uint32_t)ch * 16u;
            bb ^= ((bb >> 12) & 7u) << 4;
            bf16x8 v = *(bf16x8*)(T + bb);
            *(bf16x8*)(dstW + (size_t)kt * 512 + l * 8) = v;
        }
        return;
    }

    // ---------------- prep_a: 64 rows (4 mtiles) per block ----------------
    const int q = t & 15;
    const int part = t >> 4;
    const int m0q = blockIdx.x * 64 + q * 4;
    const uint32_t b  = (uint32_t)m0q / 784u;
    const uint32_t hw = (uint32_t)m0q % 784u;
    const float* base = in + (size_t)b * IMG_STRIDE + hw;

    float acx = 0.f, acy = 0.f, acz = 0.f, acw = 0.f;
    const int c0 = part * 32;
#pragma unroll 4
    for (int c = c0; c < c0 + 32; ++c) {
        f32x4 v = nt_load4(base + (size_t)c * HW);
        acx = fmaf(v[0], v[0], acx);
        acy = fmaf(v[1], v[1], acy);
        acz = fmaf(v[2], v[2], acz);
        acw = fmaf(v[3], v[3], acw);
        uint16_t vals[4] = { f2bf(v[0]), f2bf(v[1]), f2bf(v[2]), f2bf(v[3]) };
        const uint32_t by0 = (uint32_t)(q * 4) * 1024u + (uint32_t)c * 2u;
#pragma unroll
        for (int j = 0; j < 4; ++j) {
            uint32_t bb = by0 + (uint32_t)j * 1024u;
            bb ^= ((bb >> 12) & 7u) << 4;
            *(uint16_t*)(T + bb) = vals[j];
        }
    }
    red[part][q * 4 + 0] = acx;
    red[part][q * 4 + 1] = acy;
    red[part][q * 4 + 2] = acz;
    red[part][q * 4 + 3] = acw;
    __syncthreads();
    if (t < 64) {
        float s = 0.f;
#pragma unroll
        for (int p = 0; p < 16; ++p) s += red[p][t];
        s2[blockIdx.x * 64 + t] = s;
    }
    short* dstA = Afr + (size_t)blockIdx.x * 64 * 512;
#pragma unroll
    for (int i = 0; i < 16; ++i) {
        const int f = i * 4 + wvl;            // 0..63
        const int mtile = f >> 4;             // 0..3
        const int kt    = f & 15;             // 0..15
        const int row = mtile * 16 + (l & 15);
        const int ch  = kt * 4 + (l >> 4);
        uint32_t bb = (uint32_t)row * 1024u + (uint32_t)ch * 16u;
        bb ^= ((bb >> 12) & 7u) << 4;
        bf16x8 v = *(bf16x8*)(T + bb);
        *(bf16x8*)(dstA + (size_t)(mtile * 16 + kt) * 512 + l * 8) = v;
    }
}

// ---------------------------------------------------------------------------
// gemm14: zero-LDS, barrier-free fragment-streaming GEMM + XCD-locality remap.
//   Every fragment load = contiguous aligned 1 KB wave-load; with the remap
//   each XCD's resident working set is ~3 MB (4 A-panels + B) < 4 MB L2, so
//   loads L2-hit (~200 cy) and the depth-2 register double-buffer (one full
//   tile of MFMA ≈ 320 cy) covers them. No barriers; waves independent.
__global__ __launch_bounds__(256, 2) void gemm14_kernel(const short* __restrict__ Afr,
                                                        const short* __restrict__ Wfr,
                                                        const float* __restrict__ s2,
                                                        const float* __restrict__ w2,
                                                        float* __restrict__ out) {
    const int t = threadIdx.x;
    const int wv = t >> 6, lane = t & 63;
    const int lr = lane & 15, lg = lane >> 4;

    // XCD-locality mapping (round-14 proven): each XCD owns a contiguous
    // ~12-bm run, bn-fast inside. Bijective for 1568 = 8*196 blocks.
    const int bid = blockIdx.x;
    const int L  = (bid & 7) * 196 + (bid >> 3);
    const int bm = L >> 4;               // 0..97
    const int bn = L & 15;               // 0..15

    const int wm = (wv >> 1) * 128;        // {0,128}
    const int wn = (wv & 1) * 64;          // {0,64}

    // fragment bases: frag (m, kt) at  base + m*8192 + kt*512  (shorts)
    const short* Ab = Afr + (size_t)(bm * 16 + (wm >> 4)) * 8192 + lane * 8;
    const short* Bb = Wfr + (size_t)(bn * 8 + (wn >> 4)) * 8192 + lane * 8;

    bf16x8 a0[8], b0[4], a1[8], b1[4];
    f32x4 acc[8][4] = {};

#define LOADF(kt, aa, bb)                                                      \
    do {                                                                       \
        _Pragma("unroll") for (int m = 0; m < 8; ++m)                          \
            aa[m] = *(const bf16x8*)(Ab + (size_t)m * 8192 + (kt) * 512);      \
        _Pragma("unroll") for (int n = 0; n < 4; ++n)                          \
            bb[n] = *(const bf16x8*)(Bb + (size_t)n * 8192 + (kt) * 512);      \
    } while (0)

#define COMPUTE(aa, bb)                                                        \
    do {                                                                       \
        __builtin_amdgcn_s_setprio(1);                                         \
        _Pragma("unroll") for (int m = 0; m < 8; ++m)                          \
            _Pragma("unroll") for (int n = 0; n < 4; ++n)                      \
                acc[m][n] = __builtin_amdgcn_mfma_f32_16x16x32_bf16(           \
                    aa[m], bb[n], acc[m][n], 0, 0, 0);                         \
        __builtin_amdgcn_s_setprio(0);                                         \
    } while (0)

    LOADF(0, a0, b0);
    LOADF(1, a1, b1);

#pragma unroll
    for (int kt = 0; kt < NKT; ++kt) {
        if ((kt & 1) == 0) {
            COMPUTE(a0, b0);                       // stalls only on a0/b0 regs
            if (kt + 2 < NKT) LOADF(kt + 2, a0, b0);
        } else {
            COMPUTE(a1, b1);
            if (kt + 2 < NKT) LOADF(kt + 2, a1, b1);
        }
    }
#undef LOADF
#undef COMPUTE

    // epilogue: relu(s2 - 2*acc + w2), REGULAR f32x4 stores (nt hurt: r13)
    float wreg[4];
    int n_ok[4];
#pragma unroll
    for (int n = 0; n < 4; ++n) {
        const int n_o = bn * TBN + wn + n * 16 + lr;
        n_ok[n] = (n_o < N_TOT);
        wreg[n] = n_ok[n] ? w2[n_o] : 0.f;
    }
#pragma unroll
    for (int m = 0; m < 8; ++m) {
        const int m_r = bm * TBM + wm + m * 16 + lg * 4;   // 4-aligned, 784%4==0
        const f32x4 s2v = *(const f32x4*)(s2 + m_r);
        const uint32_t ob  = (uint32_t)m_r / 784u;
        const uint32_t ohw = (uint32_t)m_r % 784u;
        float* obase = out + (size_t)ob * OUT_BATCH + ohw;
#pragma unroll
        for (int n = 0; n < 4; ++n) {
            if (n_ok[n]) {
                const int n_o = bn * TBN + wn + n * 16 + lr;
                const f32x4 a = acc[m][n];
                f32x4 r;
                r[0] = fmaxf(s2v[0] - 2.f * a[0] + wreg[n], 0.f);
                r[1] = fmaxf(s2v[1] - 2.f * a[1] + wreg[n], 0.f);
                r[2] = fmaxf(s2v[2] - 2.f * a[2] + wreg[n], 0.f);
                r[3] = fmaxf(s2v[3] - 2.f * a[3] + wreg[n], 0.f);
                *(f32x4*)(obase + (size_t)n_o * HW) = r;
            }
        }
    }
}

// ---------------------------------------------------------------------------
extern "C" void kernel_launch(void* const* d_in, const int* in_sizes, int n_in,
                              void* d_out, int out_size, void* d_ws, size_t ws_size,
                              hipStream_t stream) {
    const float* in = (const float*)d_in[0];   // [32,512,28,28] fp32
    const float* w  = (const float*)d_in[1];   // [2000,512,1,1] fp32
    float* out = (float*)d_out;                // [32,2000,28,28] fp32

    const size_t offA  = 0;
    const size_t offW  = offA + (size_t)M_TOT * C_IN * sizeof(short);   // 25.7 MB
    const size_t offS2 = offW + (size_t)NPAD * C_IN * sizeof(short);    // +2.1 MB
    const size_t offW2 = offS2 + (size_t)M_TOT * sizeof(float);

    short* Afr = (short*)((char*)d_ws + offA);
    short* Wfr = (short*)((char*)d_ws + offW);
    float* s2  = (float*)((char*)d_ws + offS2);
    float* w2  = (float*)((char*)d_ws + offW2);

    prep_kernel<<<PREPA_BLOCKS + PREPW_BLOCKS, 256, 0, stream>>>(in, w, Afr, Wfr, s2, w2);

    // 98 m-tiles x 16 n-tiles = 1568 blocks, 2/CU, no LDS, no barriers
    gemm14_kernel<<<98 * 16, 256, 0, stream>>>(Afr, Wfr, s2, w2, out);
}

// Round 16
// 102.468 us; speedup vs baseline: 1.3540x; 1.3540x over previous
//
#include <hip/hip_runtime.h>
#include <stdint.h>

// Problem constants
constexpr int C_IN  = 512;
constexpr int HW    = 784;            // 28*28
constexpr int NB    = 32;
constexpr int M_TOT = NB * HW;        // 25088 = 196*128
constexpr int N_TOT = 2000;
constexpr int NPAD  = 2048;
constexpr int IMG_STRIDE = C_IN * HW;
constexpr int OUT_BATCH  = N_TOT * HW;

// GEMM tiling: 128x128 block, 4 waves (wave 64x64), BK=32, ring-2 LDS
// (32 KB) -> 4 blocks/CU (16 waves), XCD-locality remap.
constexpr int TBM = 128;
constexpr int TBN = 128;
constexpr int NKT = C_IN / 32;        // 16

constexpr int PREPA_BLOCKS = M_TOT / 64;   // 392
constexpr int PREPW_BLOCKS = NPAD / 4;     // 512

typedef __attribute__((ext_vector_type(8))) short bf16x8;
typedef __attribute__((ext_vector_type(4))) float f32x4;

__device__ __forceinline__ uint16_t f2bf(float f) {
    union { float f; uint32_t u; } x; x.f = f;
    return (uint16_t)((x.u + 0x8000u) >> 16);
}

__device__ __forceinline__ void gload_lds16(const void* g, void* l) {
    __builtin_amdgcn_global_load_lds(
        (const __attribute__((address_space(1))) void*)g,
        (__attribute__((address_space(3))) void*)l, 16, 0, 0);
}

// non-temporal 16B LOAD only (read-once input streams)
__device__ __forceinline__ f32x4 nt_load4(const float* p) {
    return __builtin_nontemporal_load((const f32x4*)p);
}

// ---------------------------------------------------------------------------
// prep: blocks [0,392): Abf[m][k] = bf16(input) transposed via LDS, fused s2[m]
//       blocks [392,904): Wbf[p][k] = bf16(w) (rows >= N_TOT zeroed), fused w2[p]
__global__ __launch_bounds__(256) void prep_kernel(const float* __restrict__ in,
                                                   const float* __restrict__ w,
                                                   short* __restrict__ Abf,
                                                   short* __restrict__ Wbf,
                                                   float* __restrict__ s2,
                                                   float* __restrict__ w2) {
    __shared__ __align__(16) char T[64 * 512 * 2];
    __shared__ float red[16][64];

    const int t = threadIdx.x;

    if (blockIdx.x >= PREPA_BLOCKS) {
        const int wv = t >> 6, lane = t & 63;
        const int p = (blockIdx.x - PREPA_BLOCKS) * 4 + wv;
        bf16x8 o = (bf16x8)0;
        float s = 0.f;
        if (p < N_TOT) {
            const float* base = w + (size_t)p * C_IN + lane * 8;
            f32x4 a = nt_load4(base);
            f32x4 c = nt_load4(base + 4);
            s = a[0]*a[0] + a[1]*a[1] + a[2]*a[2] + a[3]*a[3]
              + c[0]*c[0] + c[1]*c[1] + c[2]*c[2] + c[3]*c[3];
            o[0] = (short)f2bf(a[0]); o[1] = (short)f2bf(a[1]);
            o[2] = (short)f2bf(a[2]); o[3] = (short)f2bf(a[3]);
            o[4] = (short)f2bf(c[0]); o[5] = (short)f2bf(c[1]);
            o[6] = (short)f2bf(c[2]); o[7] = (short)f2bf(c[3]);
        }
        *(bf16x8*)(Wbf + (size_t)p * C_IN + lane * 8) = o;
#pragma unroll
        for (int off = 32; off; off >>= 1) s += __shfl_down(s, off);
        if (lane == 0) w2[p] = s;
        return;
    }

    const int q = t & 15;
    const int part = t >> 4;
    const int m0q = blockIdx.x * 64 + q * 4;
    const uint32_t b  = (uint32_t)m0q / 784u;
    const uint32_t hw = (uint32_t)m0q % 784u;
    const float* base = in + (size_t)b * IMG_STRIDE + hw;

    float acx = 0.f, acy = 0.f, acz = 0.f, acw = 0.f;
    const int c0 = part * 32;
#pragma unroll 4
    for (int c = c0; c < c0 + 32; ++c) {
        f32x4 v = nt_load4(base + (size_t)c * HW);
        acx = fmaf(v[0], v[0], acx);
        acy = fmaf(v[1], v[1], acy);
        acz = fmaf(v[2], v[2], acz);
        acw = fmaf(v[3], v[3], acw);
        uint16_t vals[4] = { f2bf(v[0]), f2bf(v[1]), f2bf(v[2]), f2bf(v[3]) };
        const uint32_t by0 = (uint32_t)(q * 4) * 1024u + (uint32_t)c * 2u;
#pragma unroll
        for (int j = 0; j < 4; ++j) {
            uint32_t bb = by0 + (uint32_t)j * 1024u;
            bb ^= ((bb >> 12) & 7u) << 4;
            *(uint16_t*)(T + bb) = vals[j];
        }
    }
    red[part][q * 4 + 0] = acx;
    red[part][q * 4 + 1] = acy;
    red[part][q * 4 + 2] = acz;
    red[part][q * 4 + 3] = acw;
    __syncthreads();
    if (t < 64) {
        float s = 0.f;
#pragma unroll
        for (int p = 0; p < 16; ++p) s += red[p][t];
        s2[blockIdx.x * 64 + t] = s;
    }
    short* dst = Abf + (size_t)blockIdx.x * 64 * 512;
#pragma unroll
    for (int i = 0; i < 16; ++i) {
        const int idx = i * 256 + t;
        const int row = idx >> 6, ch = idx & 63;
        uint32_t bb = (uint32_t)row * 1024u + (uint32_t)ch * 16u;
        bb ^= ((bb >> 12) & 7u) << 4;
        bf16x8 v = *(bf16x8*)(T + bb);
        *(bf16x8*)(dst + (size_t)row * 512 + ch * 8) = v;
    }
}

// ---------------------------------------------------------------------------
// gemm15: 128x128 block, 4 waves (wave 64x64, acc[4][4] = 64 AGPR), BK=32,
// ring-2 LDS (2 x 16 KB = 32 KB -> 4 blocks/CU = 16 waves, 2x gemm13's
// occupancy), XCD-locality remap (round-14 proven), measured-0-conflict slot
// swizzle, STAGE(kt+1) issued a full compute-tile before its vmcnt(0) gate.
//
// LDS buffer (16 KB): A 128 rows x 64 B at +0, B 128 rows x 64 B at +8192.
// Storage slot s of row r holds logical k-group s ^ ((r>>1)&3).
__global__ __launch_bounds__(256, 4) void gemm15_kernel(const short* __restrict__ Abf,
                                                        const short* __restrict__ Wbf,
                                                        const float* __restrict__ s2,
                                                        const float* __restrict__ w2,
                                                        float* __restrict__ out) {
    __shared__ __align__(16) char smem[32768];   // 2 x 16 KB

    const int t = threadIdx.x;
    const int wv = t >> 6, lane = t & 63;
    const int lr = lane & 15, lg = lane >> 4;

    // XCD-locality remap: bijective for 3136 = 8*392 blocks. Each XCD's
    // 128 resident blocks span ~8 A-panels (1 MB) + B (2 MB) < 4 MB L2.
    const int bid = blockIdx.x;
    const int L  = (bid & 7) * 392 + (bid >> 3);
    const int bm = L >> 4;               // 0..195
    const int bn = L & 15;               // 0..15

    const short* Ap = Abf + (size_t)bm * TBM * C_IN;
    const short* Bp = Wbf + (size_t)bn * TBN * C_IN;

    // ---- staging: instr j dest = buf + j*4096 + t*16
    //      -> row = j*64 + wv*16 + (lane>>2), storage slot = lane&3
    //      source logical k-group = (lane&3) ^ ((lane>>3)&3)
    const int srow = wv * 16 + (lane >> 2);
    const int sg   = (lane & 3) ^ ((lane >> 3) & 3);
    const short* AsrcL = Ap + (size_t)srow * C_IN + sg * 8;
    const short* BsrcL = Bp + (size_t)srow * C_IN + sg * 8;
    const int dst = t * 16;

    // ---- wave -> output subtile (64m x 64n)
    const int wm = (wv >> 1) * 64;         // {0,64}
    const int wn = (wv & 1) * 64;          // {0,64}

    // ---- ds_read: row r at 64 B stride, slot lg^((lr>>1)&3); frag stride 1024
    const int slot  = lg ^ ((lr >> 1) & 3);
    const int abase = (wm + lr) * 64 + slot * 16;
    const int bbase = 8192 + (wn + lr) * 64 + slot * 16;

    f32x4 acc[4][4] = {};

#define STAGE(tt)                                                              \
    do {                                                                       \
        char* buf_ = smem + ((tt) & 1) * 16384;                                \
        const short* as_ = AsrcL + (tt) * 32;                                  \
        const short* bs_ = BsrcL + (tt) * 32;                                  \
        gload_lds16(as_,              buf_ + dst);                             \
        gload_lds16(as_ + 64 * C_IN,  buf_ + 4096 + dst);                      \
        gload_lds16(bs_,              buf_ + 8192 + dst);                      \
        gload_lds16(bs_ + 64 * C_IN,  buf_ + 12288 + dst);                     \
    } while (0)

    // prologue: stage tile 0 and wait for it
    STAGE(0);
    asm volatile("s_waitcnt vmcnt(0)" ::: "memory");
    __builtin_amdgcn_sched_barrier(0);
    __builtin_amdgcn_s_barrier();
    __builtin_amdgcn_sched_barrier(0);

#pragma unroll
    for (int kt = 0; kt < NKT; ++kt) {
        // issue next tile's stage FIRST (buffer kt+1&1 was consumed in kt-1;
        // the entry barrier of this tile guaranteed that for all waves)
        if (kt + 1 < NKT) STAGE(kt + 1);

        const char* buf = smem + (kt & 1) * 16384;
        bf16x8 bfrag[4], afrag[4];
#pragma unroll
        for (int n = 0; n < 4; ++n)
            bfrag[n] = *(const bf16x8*)(buf + bbase + n * 1024);
#pragma unroll
        for (int m = 0; m < 4; ++m)
            afrag[m] = *(const bf16x8*)(buf + abase + m * 1024);

        __builtin_amdgcn_s_setprio(1);
#pragma unroll
        for (int m = 0; m < 4; ++m)
#pragma unroll
            for (int n = 0; n < 4; ++n)
                acc[m][n] = __builtin_amdgcn_mfma_f32_16x16x32_bf16(
                    afrag[m], bfrag[n], acc[m][n], 0, 0, 0);
        __builtin_amdgcn_s_setprio(0);

        if (kt + 1 < NKT) {
            // my stage(kt+1) landed (issued one full compute-tile ago);
            // barrier => true for all waves + all reads of buf done.
            asm volatile("s_waitcnt vmcnt(0)" ::: "memory");
            __builtin_amdgcn_sched_barrier(0);
            __builtin_amdgcn_s_barrier();
            __builtin_amdgcn_sched_barrier(0);
        }
    }
#undef STAGE

    // epilogue: relu(s2 - 2*acc + w2), regular f32x4 stores
    float wreg[4];
    int n_ok[4];
#pragma unroll
    for (int n = 0; n < 4; ++n) {
        const int n_o = bn * TBN + wn + n * 16 + lr;
        n_ok[n] = (n_o < N_TOT);
        wreg[n] = n_ok[n] ? w2[n_o] : 0.f;
    }
#pragma unroll
    for (int m = 0; m < 4; ++m) {
        const int m_r = bm * TBM + wm + m * 16 + lg * 4;   // 4-aligned, 784%4==0
        const f32x4 s2v = *(const f32x4*)(s2 + m_r);
        const uint32_t ob  = (uint32_t)m_r / 784u;
        const uint32_t ohw = (uint32_t)m_r % 784u;
        float* obase = out + (size_t)ob * OUT_BATCH + ohw;
#pragma unroll
        for (int n = 0; n < 4; ++n) {
            if (n_ok[n]) {
                const int n_o = bn * TBN + wn + n * 16 + lr;
                const f32x4 a = acc[m][n];
                f32x4 r;
                r[0] = fmaxf(s2v[0] - 2.f * a[0] + wreg[n], 0.f);
                r[1] = fmaxf(s2v[1] - 2.f * a[1] + wreg[n], 0.f);
                r[2] = fmaxf(s2v[2] - 2.f * a[2] + wreg[n], 0.f);
                r[3] = fmaxf(s2v[3] - 2.f * a[3] + wreg[n], 0.f);
                *(f32x4*)(obase + (size_t)n_o * HW) = r;
            }
        }
    }
}

// ---------------------------------------------------------------------------
extern "C" void kernel_launch(void* const* d_in, const int* in_sizes, int n_in,
                              void* d_out, int out_size, void* d_ws, size_t ws_size,
                              hipStream_t stream) {
    const float* in = (const float*)d_in[0];   // [32,512,28,28] fp32
    const float* w  = (const float*)d_in[1];   // [2000,512,1,1] fp32
    float* out = (float*)d_out;                // [32,2000,28,28] fp32

    const size_t offA  = 0;
    const size_t offW  = offA + (size_t)M_TOT * C_IN * sizeof(short);   // 25.7 MB
    const size_t offS2 = offW + (size_t)NPAD * C_IN * sizeof(short);    // +2.1 MB
    const size_t offW2 = offS2 + (size_t)M_TOT * sizeof(float);

    short* Abf = (short*)((char*)d_ws + offA);
    short* Wbf = (short*)((char*)d_ws + offW);
    float* s2  = (float*)((char*)d_ws + offS2);
    float* w2  = (float*)((char*)d_ws + offW2);

    prep_kernel<<<PREPA_BLOCKS + PREPW_BLOCKS, 256, 0, stream>>>(in, w, Abf, Wbf, s2, w2);

    // 196 m-tiles x 16 n-tiles = 3136 blocks, 4 resident per CU (3.06 rounds)
    gemm15_kernel<<<196 * 16, 256, 0, stream>>>(Abf, Wbf, s2, w2, out);
}